// Round 3
// baseline (265.326 us; speedup 1.0000x reference)
//
#include <hip/hip_runtime.h>

#define DEVI __device__ __forceinline__

typedef __attribute__((ext_vector_type(8))) short short8x;
typedef __attribute__((ext_vector_type(4))) float float4x;

DEVI float shx(float v, int m) { return __shfl_xor(v, m, 64); }

DEVI unsigned bf16r(float v) {
  unsigned u = __float_as_uint(v);
  return (u + 0x7FFF + ((u >> 16) & 1)) >> 16;
}
// split two floats into packed bf16 hi-pair and lo-pair (RNE both levels)
DEVI void split2(float a, float b, unsigned& h, unsigned& l) {
  unsigned ra = bf16r(a), rb = bf16r(b);
  float fa = __uint_as_float(ra << 16), fb = __uint_as_float(rb << 16);
  unsigned la = bf16r(a - fa), lb = bf16r(b - fb);
  h = ra | (rb << 16);
  l = la | (lb << 16);
}

// In-thread FWHT over N contiguous elements.
template <int N>
DEVI void fwht_local(float* v) {
#pragma unroll
  for (int s = 1; s < N; s <<= 1) {
#pragma unroll
    for (int k = 0; k < N; ++k) {
      if ((k & s) == 0) {
        float a = v[k], b = v[k | s];
        v[k] = a + b;
        v[k | s] = a - b;
      }
    }
  }
}

// Cross-lane xor-exchange. mask 1/2 -> DPP quad_perm; mask 4/8 -> ds_swizzle.
template <int MASK>
DEVI float lanex(float x) {
  if constexpr (MASK == 1)
    return __int_as_float(__builtin_amdgcn_update_dpp(
        0, __float_as_int(x), 0xB1, 0xF, 0xF, true));
  else if constexpr (MASK == 2)
    return __int_as_float(__builtin_amdgcn_update_dpp(
        0, __float_as_int(x), 0x4E, 0xF, 0xF, true));
  else
    return __int_as_float(__builtin_amdgcn_ds_swizzle(
        __float_as_int(x), (MASK << 10) | 0x1F));
}

template <int N, int MASK>
DEVI void xstage(float* v, bool upper) {
  const float sgn = upper ? 1.0f : -1.0f;
#pragma unroll
  for (int k = 0; k < N; ++k) {
    float u = lanex<MASK>(v[k]);
    v[k] = fmaf(sgn, v[k], u);
  }
}

// ---- legacy shuffle-based transforms (tiny k_filters only) ----
template <int N>
DEVI void xbfly(float* v, int mask, int up) {
  const float sgn = up ? 1.0f : -1.0f;
#pragma unroll
  for (int k = 0; k < N; ++k) {
    float u = shx(v[k], mask);
    v[k] = fmaf(sgn, v[k], u);
  }
}

DEVI void fwht2d32(float v[16], int t) {
  fwht_local<16>(v);
  xbfly<16>(v, 1, !(t & 1));
  const int r = t >> 1;
  xbfly<16>(v, 2, !(r & 1));
  xbfly<16>(v, 4, !(r & 2));
  xbfly<16>(v, 8, !(r & 4));
  xbfly<16>(v, 16, !(r & 8));
  xbfly<16>(v, 32, !(r & 16));
}

DEVI void fwht2d16(float v[4], int l) {
  fwht_local<4>(v);
  xbfly<4>(v, 1, !(l & 1));
  xbfly<4>(v, 2, !(l & 2));
  const int r = l >> 2;
  xbfly<4>(v, 4, !(r & 1));
  xbfly<4>(v, 8, !(r & 2));
  xbfly<4>(v, 16, !(r & 4));
  xbfly<4>(v, 32, !(r & 8));
}

// ---------------------------------------------------------------- filters
__global__ __launch_bounds__(64) void k_filters(
    const float* __restrict__ f1, const float* __restrict__ f2,
    float* __restrict__ kt1, float* __restrict__ kt2) {
  const int blk = blockIdx.x;
  const int t = threadIdx.x;
  if (blk < 32) {
    const int f = blk;
    const int r = t >> 1, h = t & 1;
    float v[16];
#pragma unroll
    for (int k = 0; k < 16; ++k) {
      const int c = h * 16 + k;
      v[k] = (r < 3 && c < 3) ? f1[f * 9 + r * 3 + c] : 0.0f;
    }
    fwht2d32(v, t);
#pragma unroll
    for (int k = 0; k < 16; ++k)
      kt1[f * 1024 + (h * 16 + k) * 32 + r] = v[k] * (1.0f / 32768.0f);
  } else {
    const int g = blk - 32;
    const int r = t >> 2, q = t & 3;
    float v[4];
#pragma unroll
    for (int j = 0; j < 4; ++j) {
      const int c = q * 4 + j;
      v[j] = (r < 3 && c < 3) ? f2[g * 9 + r * 3 + c] : 0.0f;
    }
    fwht2d16(v, t);
#pragma unroll
    for (int j = 0; j < 4; ++j)
      kt2[g * 256 + r * 16 + q * 4 + j] = v[j] * (1.0f / 4096.0f);
  }
}

// ---------------------------------------------------------- fused conv1+conv2
__global__ __launch_bounds__(256) void k_conv(
    const float* __restrict__ x, const float* __restrict__ bias1,
    const float* __restrict__ bias2, const float* __restrict__ kt1,
    const float* __restrict__ kt2, unsigned short* __restrict__ Ah,
    unsigned short* __restrict__ Al) {
  __shared__ float tb[4 * 1160];
  const int b = blockIdx.x;
  const int tid = threadIdx.x;
  const int wv = tid >> 6, t = tid & 63;
  float* buf = tb + wv * 1160;
  const int wbase = 544 * (t & 1) + (t >> 1);
  const int rbase = 34 * (t >> 1) + 16 * (t & 1);

  float Ts[16];
  {
    const float* xb = x + (size_t)b * 3072 + (t >> 1) * 32 + (t & 1) * 16;
#pragma unroll
    for (int q = 0; q < 4; ++q) {
      float4 a0 = *(const float4*)(xb + 4 * q);
      float4 a1 = *(const float4*)(xb + 1024 + 4 * q);
      float4 a2 = *(const float4*)(xb + 2048 + 4 * q);
      Ts[4 * q + 0] = a0.x + a1.x + a2.x;
      Ts[4 * q + 1] = a0.y + a1.y + a2.y;
      Ts[4 * q + 2] = a0.z + a1.z + a2.z;
      Ts[4 * q + 3] = a0.w + a1.w + a2.w;
    }
  }
  fwht_local<16>(Ts);
  xstage<16, 1>(Ts, !(t & 1));
#pragma unroll
  for (int k = 0; k < 16; ++k) buf[wbase + 34 * k] = Ts[k];
  asm volatile("" ::: "memory");
#pragma unroll
  for (int j = 0; j < 8; ++j) {
    float2 v2 = *(const float2*)&buf[rbase + 2 * j];
    Ts[2 * j] = v2.x;
    Ts[2 * j + 1] = v2.y;
  }
  asm volatile("" ::: "memory");
  fwht_local<16>(Ts);
  xstage<16, 1>(Ts, !(t & 1));

  float acc[8];
#pragma unroll
  for (int j = 0; j < 8; ++j) acc[j] = 0.0f;

  for (int i = 0; i < 8; ++i) {
    const int f = wv * 8 + i;
    const float* kp = kt1 + f * 1024 + t * 16;
    float u[16];
#pragma unroll
    for (int q = 0; q < 4; ++q) {
      float4 kv = *(const float4*)(kp + 4 * q);
      u[4 * q + 0] = Ts[4 * q + 0] * kv.x;
      u[4 * q + 1] = Ts[4 * q + 1] * kv.y;
      u[4 * q + 2] = Ts[4 * q + 2] * kv.z;
      u[4 * q + 3] = Ts[4 * q + 3] * kv.w;
    }
    fwht_local<16>(u);
    xstage<16, 1>(u, !(t & 1));
#pragma unroll
    for (int k = 0; k < 16; ++k) buf[wbase + 34 * k] = u[k];
    asm volatile("" ::: "memory");
#pragma unroll
    for (int j = 0; j < 8; ++j) {
      float2 v2 = *(const float2*)&buf[rbase + 2 * j];
      u[2 * j] = v2.x;
      u[2 * j + 1] = v2.y;
    }
    asm volatile("" ::: "memory");
    fwht_local<16>(u);
    xstage<16, 1>(u, !(t & 1));
    const float bb = bias1[f];
#pragma unroll
    for (int k = 0; k < 16; ++k) u[k] = fmaxf(u[k] + bb, 0.0f);
#pragma unroll
    for (int k = 0; k < 16; ++k) u[k] = fmaxf(u[k], lanex<2>(u[k]));
#pragma unroll
    for (int j = 0; j < 8; ++j) acc[j] += fmaxf(u[2 * j], u[2 * j + 1]);
  }

  if (!(t & 2)) {
    const int pb = (t >> 2) * 20 + (t & 1) * 8;
    *(float4*)&buf[pb] = make_float4(acc[0], acc[1], acc[2], acc[3]);
    *(float4*)&buf[pb + 4] = make_float4(acc[4], acc[5], acc[6], acc[7]);
  }
  __syncthreads();

  const int f2s = t >> 4, rr = t & 15;
  float T2[16];
#pragma unroll
  for (int q = 0; q < 4; ++q) {
    float4 s = make_float4(0.f, 0.f, 0.f, 0.f);
#pragma unroll
    for (int w2 = 0; w2 < 4; ++w2) {
      const float4 v = *(const float4*)&tb[w2 * 1160 + rr * 20 + 4 * q];
      s.x += v.x; s.y += v.y; s.z += v.z; s.w += v.w;
    }
    T2[4 * q + 0] = s.x;
    T2[4 * q + 1] = s.y;
    T2[4 * q + 2] = s.z;
    T2[4 * q + 3] = s.w;
  }
  fwht_local<16>(T2);
  xstage<16, 1>(T2, !(t & 1));
  xstage<16, 2>(T2, !(t & 2));
  xstage<16, 4>(T2, !(t & 4));
  xstage<16, 8>(T2, !(t & 8));

#pragma unroll
  for (int it = 0; it < 4; ++it) {
    const int g = wv * 16 + it * 4 + f2s;
    const float* kp2 = kt2 + g * 256 + rr * 16;
    float u[16];
#pragma unroll
    for (int q = 0; q < 4; ++q) {
      float4 kv = *(const float4*)(kp2 + 4 * q);
      u[4 * q + 0] = T2[4 * q + 0] * kv.x;
      u[4 * q + 1] = T2[4 * q + 1] * kv.y;
      u[4 * q + 2] = T2[4 * q + 2] * kv.z;
      u[4 * q + 3] = T2[4 * q + 3] * kv.w;
    }
    fwht_local<16>(u);
    xstage<16, 1>(u, !(t & 1));
    xstage<16, 2>(u, !(t & 2));
    xstage<16, 4>(u, !(t & 4));
    xstage<16, 8>(u, !(t & 8));
    const float bb = bias2[g];
#pragma unroll
    for (int k = 0; k < 16; ++k) u[k] = fmaxf(u[k] + bb, 0.0f);
#pragma unroll
    for (int k = 0; k < 16; ++k) u[k] = fmaxf(u[k], lanex<1>(u[k]));
    float p[8];
#pragma unroll
    for (int j = 0; j < 8; ++j) p[j] = fmaxf(u[2 * j], u[2 * j + 1]);
    if (!(t & 1)) {
      unsigned hh[4], ll[4];
#pragma unroll
      for (int j = 0; j < 4; ++j) split2(p[2 * j], p[2 * j + 1], hh[j], ll[j]);
      const size_t off = (size_t)b * 4096 + g * 64 + (rr >> 1) * 8;
      *(uint4*)(Ah + off) = make_uint4(hh[0], hh[1], hh[2], hh[3]);
      *(uint4*)(Al + off) = make_uint4(ll[0], ll[1], ll[2], ll[3]);
    }
  }
}

// ------------------------------------------------- W split fp32 -> bf16 hi/lo
__global__ __launch_bounds__(256) void k_wsplit(
    const float* __restrict__ W, unsigned short* __restrict__ Wh,
    unsigned short* __restrict__ Wl) {
  const int i = (blockIdx.x * 256 + threadIdx.x) * 4;
  float4 v = *(const float4*)(W + i);
  unsigned h0, l0, h1, l1;
  split2(v.x, v.y, h0, l0);
  split2(v.z, v.w, h1, l1);
  *(uint2*)(Wh + i) = make_uint2(h0, h1);
  *(uint2*)(Wl + i) = make_uint2(l0, l1);
}

// ------------------------------------------------------------------- FC1
// Split-bf16 MFMA GEMM: C[m,n] = sum_k A[m,k] W[n,k], M=B, N=512, K=4096.
// BM=128 BN=64, split-K=4 (K=1024/block), 4 waves 2x2, wave-tile 64x32.
// LDS tiles XOR-swizzled (chunk ^= row&7) -> conflict-free b128 r/w.
// Grid swizzle: 8 consecutive n-blocks of one (m,kidx) share an XCD (A L2-hot).
__global__ __launch_bounds__(256) void k_fc1(
    const unsigned short* __restrict__ Ah, const unsigned short* __restrict__ Al,
    const unsigned short* __restrict__ Wh, const unsigned short* __restrict__ Wl,
    float* __restrict__ P, int M) {
  __shared__ uint4 lds4[3072];  // Ah[0,1024) Al[1024,2048) Wh[2048,2560) Wl[2560,3072)
  const int bid = blockIdx.x;
  const int low3 = bid & 7, rest = bid >> 3;
  const int nt = rest & 7;
  const int c = ((rest >> 3) << 3) | low3;   // (mt,kidx) chunk id
  const int mt = c >> 2, kidx = c & 3;
  const int m0 = mt * 128, n0 = nt * 64, k0 = kidx * 1024;

  const int tid = threadIdx.x;
  const int wv = tid >> 6, lane = tid & 63;
  const int wm = (wv >> 1) * 64, wn = (wv & 1) * 32;
  const int lm = lane & 15, lq = lane >> 4;
  const int sr = tid >> 3, sc = tid & 7;  // staging (row-in-32, chunk)

  float4x acc[4][2];
#pragma unroll
  for (int i = 0; i < 4; ++i)
#pragma unroll
    for (int j = 0; j < 2; ++j) acc[i][j] = (float4x){0.f, 0.f, 0.f, 0.f};

  for (int kk = 0; kk < 1024; kk += 64) {
    uint4 tmp[12];
#pragma unroll
    for (int it = 0; it < 4; ++it) {
      const size_t go = (size_t)(m0 + it * 32 + sr) * 4096 + (k0 + kk + sc * 8);
      tmp[it] = *(const uint4*)(Ah + go);
      tmp[4 + it] = *(const uint4*)(Al + go);
    }
#pragma unroll
    for (int it = 0; it < 2; ++it) {
      const size_t go = (size_t)(n0 + it * 32 + sr) * 4096 + (k0 + kk + sc * 8);
      tmp[8 + it] = *(const uint4*)(Wh + go);
      tmp[10 + it] = *(const uint4*)(Wl + go);
    }
    __syncthreads();  // prior compute done before overwrite
    const int swc = sc ^ (sr & 7);
#pragma unroll
    for (int it = 0; it < 4; ++it) {
      lds4[(it * 32 + sr) * 8 + swc] = tmp[it];
      lds4[1024 + (it * 32 + sr) * 8 + swc] = tmp[4 + it];
    }
#pragma unroll
    for (int it = 0; it < 2; ++it) {
      lds4[2048 + (it * 32 + sr) * 8 + swc] = tmp[8 + it];
      lds4[2560 + (it * 32 + sr) * 8 + swc] = tmp[10 + it];
    }
    __syncthreads();
#pragma unroll
    for (int ks = 0; ks < 2; ++ks) {
      const int ch = ks * 4 + lq;
      short8x a_h[4], a_l[4], b_h[2], b_l[2];
#pragma unroll
      for (int fm = 0; fm < 4; ++fm) {
        const int r = wm + fm * 16 + lm;
        const int s = r * 8 + (ch ^ (r & 7));
        a_h[fm] = *(const short8x*)&lds4[s];
        a_l[fm] = *(const short8x*)&lds4[1024 + s];
      }
#pragma unroll
      for (int fn = 0; fn < 2; ++fn) {
        const int r = wn + fn * 16 + lm;
        const int s = r * 8 + (ch ^ (r & 7));
        b_h[fn] = *(const short8x*)&lds4[2048 + s];
        b_l[fn] = *(const short8x*)&lds4[2560 + s];
      }
#pragma unroll
      for (int fm = 0; fm < 4; ++fm)
#pragma unroll
        for (int fn = 0; fn < 2; ++fn) {
          acc[fm][fn] = __builtin_amdgcn_mfma_f32_16x16x32_bf16(
              a_h[fm], b_h[fn], acc[fm][fn], 0, 0, 0);
          acc[fm][fn] = __builtin_amdgcn_mfma_f32_16x16x32_bf16(
              a_h[fm], b_l[fn], acc[fm][fn], 0, 0, 0);
          acc[fm][fn] = __builtin_amdgcn_mfma_f32_16x16x32_bf16(
              a_l[fm], b_h[fn], acc[fm][fn], 0, 0, 0);
        }
    }
  }
  float* Pp = P + (size_t)kidx * ((size_t)M * 512);
#pragma unroll
  for (int fm = 0; fm < 4; ++fm)
#pragma unroll
    for (int fn = 0; fn < 2; ++fn)
#pragma unroll
      for (int i = 0; i < 4; ++i) {
        const int r = m0 + wm + fm * 16 + lq * 4 + i;
        const int cc = n0 + wn + fn * 16 + lm;
        Pp[(size_t)r * 512 + cc] = acc[fm][fn][i];
      }
}

__global__ __launch_bounds__(256) void k_fc1red4(
    const float* __restrict__ P, const float* __restrict__ bias,
    float* __restrict__ O, int total) {
  const int idx = (blockIdx.x * 256 + threadIdx.x) * 4;
  const float4 p0 = *(const float4*)(P + idx);
  const float4 p1 = *(const float4*)(P + (size_t)total + idx);
  const float4 p2 = *(const float4*)(P + (size_t)2 * total + idx);
  const float4 p3 = *(const float4*)(P + (size_t)3 * total + idx);
  const float4 bv = *(const float4*)(bias + (idx & 511));
  float4 o;
  o.x = fmaxf(p0.x + p1.x + p2.x + p3.x + bv.x, 0.0f);
  o.y = fmaxf(p0.y + p1.y + p2.y + p3.y + bv.y, 0.0f);
  o.z = fmaxf(p0.z + p1.z + p2.z + p3.z + bv.z, 0.0f);
  o.w = fmaxf(p0.w + p1.w + p2.w + p3.w + bv.w, 0.0f);
  *(float4*)(O + idx) = o;
}

// ------------------------------------------------------------- FC2+softmax
__global__ __launch_bounds__(256) void k_fc2(
    const float* __restrict__ X, const float* __restrict__ W,
    const float* __restrict__ bias, float* __restrict__ out) {
  const int wv = threadIdx.x >> 6, t = threadIdx.x & 63;
  const int b = blockIdx.x * 4 + wv;
  const float* xr = X + (size_t)b * 512 + t * 8;
  const float4 x0 = *(const float4*)xr;
  const float4 x1 = *(const float4*)(xr + 4);
  float z[10];
#pragma unroll
  for (int o = 0; o < 10; ++o) {
    const float* wr = W + o * 512 + t * 8;
    const float4 w0 = *(const float4*)wr;
    const float4 w1 = *(const float4*)(wr + 4);
    float s = x0.x * w0.x;
    s = fmaf(x0.y, w0.y, s);
    s = fmaf(x0.z, w0.z, s);
    s = fmaf(x0.w, w0.w, s);
    s = fmaf(x1.x, w1.x, s);
    s = fmaf(x1.y, w1.y, s);
    s = fmaf(x1.z, w1.z, s);
    s = fmaf(x1.w, w1.w, s);
    z[o] = s;
  }
#pragma unroll
  for (int m = 1; m < 64; m <<= 1) {
#pragma unroll
    for (int o = 0; o < 10; ++o) z[o] += shx(z[o], m);
  }
#pragma unroll
  for (int o = 0; o < 10; ++o) z[o] += bias[o];
  float mx = z[0];
#pragma unroll
  for (int o = 1; o < 10; ++o) mx = fmaxf(mx, z[o]);
  float e[10];
  float ssum = 0.0f;
#pragma unroll
  for (int o = 0; o < 10; ++o) {
    e[o] = expf(z[o] - mx);
    ssum += e[o];
  }
  const float inv = 1.0f / ssum;
  if (t == 0) {
    float* dst = out + (size_t)b * 10;
#pragma unroll
    for (int o = 0; o < 10; ++o) dst[o] = e[o] * inv;
  }
}

// ------------------------------------------------------------------ launch
extern "C" void kernel_launch(void* const* d_in, const int* in_sizes, int n_in,
                              void* d_out, int out_size, void* d_ws,
                              size_t ws_size, hipStream_t stream) {
  const float* x = (const float*)d_in[0];
  const float* f1 = (const float*)d_in[1];
  const float* b1 = (const float*)d_in[2];
  const float* f2 = (const float*)d_in[3];
  const float* b2 = (const float*)d_in[4];
  const float* fc1w = (const float*)d_in[5];
  const float* fc1b = (const float*)d_in[6];
  const float* fc2w = (const float*)d_in[7];
  const float* fc2b = (const float*)d_in[8];
  float* out = (float*)d_out;
  const int B = in_sizes[0] / 3072;  // 2048

  char* w = (char*)d_ws;
  float* kt1 = (float*)w;                                    // 32768 f
  float* kt2 = (float*)(w + 131072);                         // 16384 f
  unsigned short* Ah = (unsigned short*)(w + 196608);        // B*4096 us
  unsigned short* Al = (unsigned short*)(w + 196608 + (size_t)B * 8192);
  unsigned short* Wh = (unsigned short*)(w + 196608 + (size_t)2 * B * 8192);
  unsigned short* Wl =
      (unsigned short*)(w + 196608 + (size_t)2 * B * 8192 + 4194304);
  float* P = (float*)(w + 196608 + (size_t)2 * B * 8192 + 8388608);
  float* fc1o = (float*)(w + 196608 + (size_t)2 * B * 8192 + 8388608 +
                         (size_t)4 * B * 2048);

  hipLaunchKernelGGL(k_filters, dim3(96), dim3(64), 0, stream, f1, f2, kt1,
                     kt2);
  hipLaunchKernelGGL(k_wsplit, dim3(2048), dim3(256), 0, stream, fc1w, Wh, Wl);
  hipLaunchKernelGGL(k_conv, dim3(B), dim3(256), 0, stream, x, b1, b2, kt1,
                     kt2, Ah, Al);
  hipLaunchKernelGGL(k_fc1, dim3((B / 128) * 32), dim3(256), 0, stream, Ah, Al,
                     Wh, Wl, P, B);
  hipLaunchKernelGGL(k_fc1red4, dim3((B * 512) / 1024), dim3(256), 0, stream,
                     P, fc1b, fc1o, B * 512);
  hipLaunchKernelGGL(k_fc2, dim3(B / 4), dim3(256), 0, stream, fc1o, fc2w,
                     fc2b, out);
}

// Round 4
// 175.898 us; speedup vs baseline: 1.5084x; 1.5084x over previous
//
#include <hip/hip_runtime.h>

#define DEVI __device__ __forceinline__

typedef __attribute__((ext_vector_type(8))) short short8x;
typedef __attribute__((ext_vector_type(4))) float float4x;

DEVI float shx(float v, int m) { return __shfl_xor(v, m, 64); }

DEVI unsigned bf16r(float v) {
  unsigned u = __float_as_uint(v);
  return (u + 0x7FFF + ((u >> 16) & 1)) >> 16;
}
// split two floats into packed bf16 hi-pair and lo-pair (RNE both levels)
DEVI void split2(float a, float b, unsigned& h, unsigned& l) {
  unsigned ra = bf16r(a), rb = bf16r(b);
  float fa = __uint_as_float(ra << 16), fb = __uint_as_float(rb << 16);
  unsigned la = bf16r(a - fa), lb = bf16r(b - fb);
  h = ra | (rb << 16);
  l = la | (lb << 16);
}

// async global->LDS, 16B per lane; LDS dest = wave-uniform base + lane*16
DEVI void gload16(const void* g, void* l) {
  __builtin_amdgcn_global_load_lds(
      (const __attribute__((address_space(1))) void*)g,
      (__attribute__((address_space(3))) void*)l, 16, 0, 0);
}

// In-thread FWHT over N contiguous elements.
template <int N>
DEVI void fwht_local(float* v) {
#pragma unroll
  for (int s = 1; s < N; s <<= 1) {
#pragma unroll
    for (int k = 0; k < N; ++k) {
      if ((k & s) == 0) {
        float a = v[k], b = v[k | s];
        v[k] = a + b;
        v[k | s] = a - b;
      }
    }
  }
}

// Cross-lane xor-exchange. mask 1/2 -> DPP quad_perm; mask 4/8 -> ds_swizzle.
template <int MASK>
DEVI float lanex(float x) {
  if constexpr (MASK == 1)
    return __int_as_float(__builtin_amdgcn_update_dpp(
        0, __float_as_int(x), 0xB1, 0xF, 0xF, true));
  else if constexpr (MASK == 2)
    return __int_as_float(__builtin_amdgcn_update_dpp(
        0, __float_as_int(x), 0x4E, 0xF, 0xF, true));
  else
    return __int_as_float(__builtin_amdgcn_ds_swizzle(
        __float_as_int(x), (MASK << 10) | 0x1F));
}

template <int N, int MASK>
DEVI void xstage(float* v, bool upper) {
  const float sgn = upper ? 1.0f : -1.0f;
#pragma unroll
  for (int k = 0; k < N; ++k) {
    float u = lanex<MASK>(v[k]);
    v[k] = fmaf(sgn, v[k], u);
  }
}

// ---- legacy shuffle-based transforms (tiny k_filters only) ----
template <int N>
DEVI void xbfly(float* v, int mask, int up) {
  const float sgn = up ? 1.0f : -1.0f;
#pragma unroll
  for (int k = 0; k < N; ++k) {
    float u = shx(v[k], mask);
    v[k] = fmaf(sgn, v[k], u);
  }
}

DEVI void fwht2d32(float v[16], int t) {
  fwht_local<16>(v);
  xbfly<16>(v, 1, !(t & 1));
  const int r = t >> 1;
  xbfly<16>(v, 2, !(r & 1));
  xbfly<16>(v, 4, !(r & 2));
  xbfly<16>(v, 8, !(r & 4));
  xbfly<16>(v, 16, !(r & 8));
  xbfly<16>(v, 32, !(r & 16));
}

DEVI void fwht2d16(float v[4], int l) {
  fwht_local<4>(v);
  xbfly<4>(v, 1, !(l & 1));
  xbfly<4>(v, 2, !(l & 2));
  const int r = l >> 2;
  xbfly<4>(v, 4, !(r & 1));
  xbfly<4>(v, 8, !(r & 2));
  xbfly<4>(v, 16, !(r & 4));
  xbfly<4>(v, 32, !(r & 8));
}

// ---------------------------------------------------------------- filters
__global__ __launch_bounds__(64) void k_filters(
    const float* __restrict__ f1, const float* __restrict__ f2,
    float* __restrict__ kt1, float* __restrict__ kt2) {
  const int blk = blockIdx.x;
  const int t = threadIdx.x;
  if (blk < 32) {
    const int f = blk;
    const int r = t >> 1, h = t & 1;
    float v[16];
#pragma unroll
    for (int k = 0; k < 16; ++k) {
      const int c = h * 16 + k;
      v[k] = (r < 3 && c < 3) ? f1[f * 9 + r * 3 + c] : 0.0f;
    }
    fwht2d32(v, t);
#pragma unroll
    for (int k = 0; k < 16; ++k)
      kt1[f * 1024 + (h * 16 + k) * 32 + r] = v[k] * (1.0f / 32768.0f);
  } else {
    const int g = blk - 32;
    const int r = t >> 2, q = t & 3;
    float v[4];
#pragma unroll
    for (int j = 0; j < 4; ++j) {
      const int c = q * 4 + j;
      v[j] = (r < 3 && c < 3) ? f2[g * 9 + r * 3 + c] : 0.0f;
    }
    fwht2d16(v, t);
#pragma unroll
    for (int j = 0; j < 4; ++j)
      kt2[g * 256 + r * 16 + q * 4 + j] = v[j] * (1.0f / 4096.0f);
  }
}

// ---------------------------------------------------------- fused conv1+conv2
__global__ __launch_bounds__(256) void k_conv(
    const float* __restrict__ x, const float* __restrict__ bias1,
    const float* __restrict__ bias2, const float* __restrict__ kt1,
    const float* __restrict__ kt2, unsigned short* __restrict__ Ah,
    unsigned short* __restrict__ Al) {
  __shared__ float tb[4 * 1160];
  const int b = blockIdx.x;
  const int tid = threadIdx.x;
  const int wv = tid >> 6, t = tid & 63;
  float* buf = tb + wv * 1160;
  const int wbase = 544 * (t & 1) + (t >> 1);
  const int rbase = 34 * (t >> 1) + 16 * (t & 1);

  float Ts[16];
  {
    const float* xb = x + (size_t)b * 3072 + (t >> 1) * 32 + (t & 1) * 16;
#pragma unroll
    for (int q = 0; q < 4; ++q) {
      float4 a0 = *(const float4*)(xb + 4 * q);
      float4 a1 = *(const float4*)(xb + 1024 + 4 * q);
      float4 a2 = *(const float4*)(xb + 2048 + 4 * q);
      Ts[4 * q + 0] = a0.x + a1.x + a2.x;
      Ts[4 * q + 1] = a0.y + a1.y + a2.y;
      Ts[4 * q + 2] = a0.z + a1.z + a2.z;
      Ts[4 * q + 3] = a0.w + a1.w + a2.w;
    }
  }
  fwht_local<16>(Ts);
  xstage<16, 1>(Ts, !(t & 1));
#pragma unroll
  for (int k = 0; k < 16; ++k) buf[wbase + 34 * k] = Ts[k];
  asm volatile("" ::: "memory");
#pragma unroll
  for (int j = 0; j < 8; ++j) {
    float2 v2 = *(const float2*)&buf[rbase + 2 * j];
    Ts[2 * j] = v2.x;
    Ts[2 * j + 1] = v2.y;
  }
  asm volatile("" ::: "memory");
  fwht_local<16>(Ts);
  xstage<16, 1>(Ts, !(t & 1));

  float acc[8];
#pragma unroll
  for (int j = 0; j < 8; ++j) acc[j] = 0.0f;

  for (int i = 0; i < 8; ++i) {
    const int f = wv * 8 + i;
    const float* kp = kt1 + f * 1024 + t * 16;
    float u[16];
#pragma unroll
    for (int q = 0; q < 4; ++q) {
      float4 kv = *(const float4*)(kp + 4 * q);
      u[4 * q + 0] = Ts[4 * q + 0] * kv.x;
      u[4 * q + 1] = Ts[4 * q + 1] * kv.y;
      u[4 * q + 2] = Ts[4 * q + 2] * kv.z;
      u[4 * q + 3] = Ts[4 * q + 3] * kv.w;
    }
    fwht_local<16>(u);
    xstage<16, 1>(u, !(t & 1));
#pragma unroll
    for (int k = 0; k < 16; ++k) buf[wbase + 34 * k] = u[k];
    asm volatile("" ::: "memory");
#pragma unroll
    for (int j = 0; j < 8; ++j) {
      float2 v2 = *(const float2*)&buf[rbase + 2 * j];
      u[2 * j] = v2.x;
      u[2 * j + 1] = v2.y;
    }
    asm volatile("" ::: "memory");
    fwht_local<16>(u);
    xstage<16, 1>(u, !(t & 1));
    const float bb = bias1[f];
#pragma unroll
    for (int k = 0; k < 16; ++k) u[k] = fmaxf(u[k] + bb, 0.0f);
#pragma unroll
    for (int k = 0; k < 16; ++k) u[k] = fmaxf(u[k], lanex<2>(u[k]));
#pragma unroll
    for (int j = 0; j < 8; ++j) acc[j] += fmaxf(u[2 * j], u[2 * j + 1]);
  }

  if (!(t & 2)) {
    const int pb = (t >> 2) * 20 + (t & 1) * 8;
    *(float4*)&buf[pb] = make_float4(acc[0], acc[1], acc[2], acc[3]);
    *(float4*)&buf[pb + 4] = make_float4(acc[4], acc[5], acc[6], acc[7]);
  }
  __syncthreads();

  const int f2s = t >> 4, rr = t & 15;
  float T2[16];
#pragma unroll
  for (int q = 0; q < 4; ++q) {
    float4 s = make_float4(0.f, 0.f, 0.f, 0.f);
#pragma unroll
    for (int w2 = 0; w2 < 4; ++w2) {
      const float4 v = *(const float4*)&tb[w2 * 1160 + rr * 20 + 4 * q];
      s.x += v.x; s.y += v.y; s.z += v.z; s.w += v.w;
    }
    T2[4 * q + 0] = s.x;
    T2[4 * q + 1] = s.y;
    T2[4 * q + 2] = s.z;
    T2[4 * q + 3] = s.w;
  }
  fwht_local<16>(T2);
  xstage<16, 1>(T2, !(t & 1));
  xstage<16, 2>(T2, !(t & 2));
  xstage<16, 4>(T2, !(t & 4));
  xstage<16, 8>(T2, !(t & 8));

#pragma unroll
  for (int it = 0; it < 4; ++it) {
    const int g = wv * 16 + it * 4 + f2s;
    const float* kp2 = kt2 + g * 256 + rr * 16;
    float u[16];
#pragma unroll
    for (int q = 0; q < 4; ++q) {
      float4 kv = *(const float4*)(kp2 + 4 * q);
      u[4 * q + 0] = T2[4 * q + 0] * kv.x;
      u[4 * q + 1] = T2[4 * q + 1] * kv.y;
      u[4 * q + 2] = T2[4 * q + 2] * kv.z;
      u[4 * q + 3] = T2[4 * q + 3] * kv.w;
    }
    fwht_local<16>(u);
    xstage<16, 1>(u, !(t & 1));
    xstage<16, 2>(u, !(t & 2));
    xstage<16, 4>(u, !(t & 4));
    xstage<16, 8>(u, !(t & 8));
    const float bb = bias2[g];
#pragma unroll
    for (int k = 0; k < 16; ++k) u[k] = fmaxf(u[k] + bb, 0.0f);
#pragma unroll
    for (int k = 0; k < 16; ++k) u[k] = fmaxf(u[k], lanex<1>(u[k]));
    float p[8];
#pragma unroll
    for (int j = 0; j < 8; ++j) p[j] = fmaxf(u[2 * j], u[2 * j + 1]);
    if (!(t & 1)) {
      unsigned hh[4], ll[4];
#pragma unroll
      for (int j = 0; j < 4; ++j) split2(p[2 * j], p[2 * j + 1], hh[j], ll[j]);
      const size_t off = (size_t)b * 4096 + g * 64 + (rr >> 1) * 8;
      *(uint4*)(Ah + off) = make_uint4(hh[0], hh[1], hh[2], hh[3]);
      *(uint4*)(Al + off) = make_uint4(ll[0], ll[1], ll[2], ll[3]);
    }
  }
}

// ------------------------------------------------- W split fp32 -> bf16 hi/lo
__global__ __launch_bounds__(256) void k_wsplit(
    const float* __restrict__ W, unsigned short* __restrict__ Wh,
    unsigned short* __restrict__ Wl) {
  const int i = (blockIdx.x * 256 + threadIdx.x) * 4;
  float4 v = *(const float4*)(W + i);
  unsigned h0, l0, h1, l1;
  split2(v.x, v.y, h0, l0);
  split2(v.z, v.w, h1, l1);
  *(uint2*)(Wh + i) = make_uint2(h0, h1);
  *(uint2*)(Wl + i) = make_uint2(l0, l1);
}

// ------------------------------------------------------------------- FC1
// Split-bf16 MFMA GEMM, BM=128 BN=64 BK=64, split-K=4.
// Staging via global_load_lds (no VGPR round-trip, no spill):
//   LDS linear rows of 128B; per-lane GLOBAL source pre-swizzled by the
//   involution chunk^=(row&7); ds_read applies the same XOR -> conflict-free.
__global__ __launch_bounds__(256) void k_fc1(
    const unsigned short* __restrict__ Ah, const unsigned short* __restrict__ Al,
    const unsigned short* __restrict__ Wh, const unsigned short* __restrict__ Wl,
    float* __restrict__ P, int M) {
  // bytes: Ah [0,16384) Al [16384,32768) Wh [32768,40960) Wl [40960,49152)
  __shared__ __align__(16) unsigned char lds[49152];
  const int bid = blockIdx.x;
  const int low3 = bid & 7, rest = bid >> 3;
  const int nt = rest & 7;
  const int c = ((rest >> 3) << 3) | low3;  // (mt,kidx) chunk id
  const int mt = c >> 2, kidx = c & 3;
  const int m0 = mt * 128, n0 = nt * 64, k0 = kidx * 1024;

  const int tid = threadIdx.x;
  const int wv = tid >> 6, lane = tid & 63;
  const int wm = (wv >> 1) * 64, wn = (wv & 1) * 32;
  const int lm = lane & 15, lq = lane >> 4;
  const int lr = lane >> 3, lc = lane & 7;  // staging: row-in-issue, chunk

  float4x acc[4][2];
#pragma unroll
  for (int i = 0; i < 4; ++i)
#pragma unroll
    for (int j = 0; j < 2; ++j) acc[i][j] = (float4x){0.f, 0.f, 0.f, 0.f};

  for (int kk = 0; kk < 1024; kk += 64) {
    const int kcol = k0 + kk;
    // ---- stage A (hi/lo): wave wv rows wv*32..+31, 4 issues x 8 rows
#pragma unroll
    for (int it = 0; it < 4; ++it) {
      const int rbase = wv * 32 + it * 8;
      const int r = rbase + lr;
      const size_t go = (size_t)(m0 + r) * 4096 + kcol + (lc ^ (r & 7)) * 8;
      gload16(Ah + go, lds + rbase * 128);
      gload16(Al + go, lds + 16384 + rbase * 128);
    }
    // ---- stage W (hi/lo): wave wv rows wv*16..+15, 2 issues x 8 rows
#pragma unroll
    for (int it = 0; it < 2; ++it) {
      const int rbase = wv * 16 + it * 8;
      const int r = rbase + lr;
      const size_t go = (size_t)(n0 + r) * 4096 + kcol + (lc ^ (r & 7)) * 8;
      gload16(Wh + go, lds + 32768 + rbase * 128);
      gload16(Wl + go, lds + 40960 + rbase * 128);
    }
    __syncthreads();  // drains vmcnt(0): staging complete

    const uint4* l4 = (const uint4*)lds;
#pragma unroll
    for (int ks = 0; ks < 2; ++ks) {
      const int ch = ks * 4 + lq;
      short8x a_h[4], a_l[4], b_h[2], b_l[2];
#pragma unroll
      for (int fm = 0; fm < 4; ++fm) {
        const int r = wm + fm * 16 + lm;
        const int s = r * 8 + (ch ^ (r & 7));
        a_h[fm] = *(const short8x*)&l4[s];
        a_l[fm] = *(const short8x*)&l4[1024 + s];
      }
#pragma unroll
      for (int fn = 0; fn < 2; ++fn) {
        const int r = wn + fn * 16 + lm;
        const int s = r * 8 + (ch ^ (r & 7));
        b_h[fn] = *(const short8x*)&l4[2048 + s];
        b_l[fn] = *(const short8x*)&l4[2560 + s];
      }
#pragma unroll
      for (int fm = 0; fm < 4; ++fm)
#pragma unroll
        for (int fn = 0; fn < 2; ++fn) {
          acc[fm][fn] = __builtin_amdgcn_mfma_f32_16x16x32_bf16(
              a_h[fm], b_h[fn], acc[fm][fn], 0, 0, 0);
          acc[fm][fn] = __builtin_amdgcn_mfma_f32_16x16x32_bf16(
              a_h[fm], b_l[fn], acc[fm][fn], 0, 0, 0);
          acc[fm][fn] = __builtin_amdgcn_mfma_f32_16x16x32_bf16(
              a_l[fm], b_h[fn], acc[fm][fn], 0, 0, 0);
        }
    }
    __syncthreads();  // reads done before next stage overwrites
  }

  float* Pp = P + (size_t)kidx * ((size_t)M * 512);
#pragma unroll
  for (int fm = 0; fm < 4; ++fm)
#pragma unroll
    for (int fn = 0; fn < 2; ++fn)
#pragma unroll
      for (int i = 0; i < 4; ++i) {
        const int r = m0 + wm + fm * 16 + lq * 4 + i;
        const int cc = n0 + wn + fn * 16 + lm;
        Pp[(size_t)r * 512 + cc] = acc[fm][fn][i];
      }
}

__global__ __launch_bounds__(256) void k_fc1red4(
    const float* __restrict__ P, const float* __restrict__ bias,
    float* __restrict__ O, int total) {
  const int idx = (blockIdx.x * 256 + threadIdx.x) * 4;
  const float4 p0 = *(const float4*)(P + idx);
  const float4 p1 = *(const float4*)(P + (size_t)total + idx);
  const float4 p2 = *(const float4*)(P + (size_t)2 * total + idx);
  const float4 p3 = *(const float4*)(P + (size_t)3 * total + idx);
  const float4 bv = *(const float4*)(bias + (idx & 511));
  float4 o;
  o.x = fmaxf(p0.x + p1.x + p2.x + p3.x + bv.x, 0.0f);
  o.y = fmaxf(p0.y + p1.y + p2.y + p3.y + bv.y, 0.0f);
  o.z = fmaxf(p0.z + p1.z + p2.z + p3.z + bv.z, 0.0f);
  o.w = fmaxf(p0.w + p1.w + p2.w + p3.w + bv.w, 0.0f);
  *(float4*)(O + idx) = o;
}

// ------------------------------------------------------------- FC2+softmax
__global__ __launch_bounds__(256) void k_fc2(
    const float* __restrict__ X, const float* __restrict__ W,
    const float* __restrict__ bias, float* __restrict__ out) {
  const int wv = threadIdx.x >> 6, t = threadIdx.x & 63;
  const int b = blockIdx.x * 4 + wv;
  const float* xr = X + (size_t)b * 512 + t * 8;
  const float4 x0 = *(const float4*)xr;
  const float4 x1 = *(const float4*)(xr + 4);
  float z[10];
#pragma unroll
  for (int o = 0; o < 10; ++o) {
    const float* wr = W + o * 512 + t * 8;
    const float4 w0 = *(const float4*)wr;
    const float4 w1 = *(const float4*)(wr + 4);
    float s = x0.x * w0.x;
    s = fmaf(x0.y, w0.y, s);
    s = fmaf(x0.z, w0.z, s);
    s = fmaf(x0.w, w0.w, s);
    s = fmaf(x1.x, w1.x, s);
    s = fmaf(x1.y, w1.y, s);
    s = fmaf(x1.z, w1.z, s);
    s = fmaf(x1.w, w1.w, s);
    z[o] = s;
  }
#pragma unroll
  for (int m = 1; m < 64; m <<= 1) {
#pragma unroll
    for (int o = 0; o < 10; ++o) z[o] += shx(z[o], m);
  }
#pragma unroll
  for (int o = 0; o < 10; ++o) z[o] += bias[o];
  float mx = z[0];
#pragma unroll
  for (int o = 1; o < 10; ++o) mx = fmaxf(mx, z[o]);
  float e[10];
  float ssum = 0.0f;
#pragma unroll
  for (int o = 0; o < 10; ++o) {
    e[o] = expf(z[o] - mx);
    ssum += e[o];
  }
  const float inv = 1.0f / ssum;
  if (t == 0) {
    float* dst = out + (size_t)b * 10;
#pragma unroll
    for (int o = 0; o < 10; ++o) dst[o] = e[o] * inv;
  }
}

// ------------------------------------------------------------------ launch
extern "C" void kernel_launch(void* const* d_in, const int* in_sizes, int n_in,
                              void* d_out, int out_size, void* d_ws,
                              size_t ws_size, hipStream_t stream) {
  const float* x = (const float*)d_in[0];
  const float* f1 = (const float*)d_in[1];
  const float* b1 = (const float*)d_in[2];
  const float* f2 = (const float*)d_in[3];
  const float* b2 = (const float*)d_in[4];
  const float* fc1w = (const float*)d_in[5];
  const float* fc1b = (const float*)d_in[6];
  const float* fc2w = (const float*)d_in[7];
  const float* fc2b = (const float*)d_in[8];
  float* out = (float*)d_out;
  const int B = in_sizes[0] / 3072;  // 2048

  char* w = (char*)d_ws;
  float* kt1 = (float*)w;                                    // 32768 f
  float* kt2 = (float*)(w + 131072);                         // 16384 f
  unsigned short* Ah = (unsigned short*)(w + 196608);        // B*4096 us
  unsigned short* Al = (unsigned short*)(w + 196608 + (size_t)B * 8192);
  unsigned short* Wh = (unsigned short*)(w + 196608 + (size_t)2 * B * 8192);
  unsigned short* Wl =
      (unsigned short*)(w + 196608 + (size_t)2 * B * 8192 + 4194304);
  float* P = (float*)(w + 196608 + (size_t)2 * B * 8192 + 8388608);
  float* fc1o = (float*)(w + 196608 + (size_t)2 * B * 8192 + 8388608 +
                         (size_t)4 * B * 2048);

  hipLaunchKernelGGL(k_filters, dim3(96), dim3(64), 0, stream, f1, f2, kt1,
                     kt2);
  hipLaunchKernelGGL(k_wsplit, dim3(2048), dim3(256), 0, stream, fc1w, Wh, Wl);
  hipLaunchKernelGGL(k_conv, dim3(B), dim3(256), 0, stream, x, b1, b2, kt1,
                     kt2, Ah, Al);
  hipLaunchKernelGGL(k_fc1, dim3((B / 128) * 32), dim3(256), 0, stream, Ah, Al,
                     Wh, Wl, P, B);
  hipLaunchKernelGGL(k_fc1red4, dim3((B * 512) / 1024), dim3(256), 0, stream,
                     P, fc1b, fc1o, B * 512);
  hipLaunchKernelGGL(k_fc2, dim3(B / 4), dim3(256), 0, stream, fc1o, fc2w,
                     fc2b, out);
}

// Round 5
// 155.301 us; speedup vs baseline: 1.7085x; 1.1326x over previous
//
#include <hip/hip_runtime.h>

#define DEVI __device__ __forceinline__

typedef __attribute__((ext_vector_type(8))) short short8x;
typedef __attribute__((ext_vector_type(4))) float float4x;

DEVI float shx(float v, int m) { return __shfl_xor(v, m, 64); }

DEVI unsigned bf16r(float v) {
  unsigned u = __float_as_uint(v);
  return (u + 0x7FFF + ((u >> 16) & 1)) >> 16;
}
// split two floats into packed bf16 hi-pair and lo-pair (RNE both levels)
DEVI void split2(float a, float b, unsigned& h, unsigned& l) {
  unsigned ra = bf16r(a), rb = bf16r(b);
  float fa = __uint_as_float(ra << 16), fb = __uint_as_float(rb << 16);
  unsigned la = bf16r(a - fa), lb = bf16r(b - fb);
  h = ra | (rb << 16);
  l = la | (lb << 16);
}

// async global->LDS, 16B per lane; LDS dest = wave-uniform base + lane*16
DEVI void gload16(const void* g, void* l) {
  __builtin_amdgcn_global_load_lds(
      (const __attribute__((address_space(1))) void*)g,
      (__attribute__((address_space(3))) void*)l, 16, 0, 0);
}

// Cross-lane xor-exchange. mask 1/2 -> DPP quad_perm; mask 4/8 -> ds_swizzle.
template <int MASK>
DEVI float lanex(float x) {
  if constexpr (MASK == 1)
    return __int_as_float(__builtin_amdgcn_update_dpp(
        0, __float_as_int(x), 0xB1, 0xF, 0xF, true));
  else if constexpr (MASK == 2)
    return __int_as_float(__builtin_amdgcn_update_dpp(
        0, __float_as_int(x), 0x4E, 0xF, 0xF, true));
  else
    return __int_as_float(__builtin_amdgcn_ds_swizzle(
        __float_as_int(x), (MASK << 10) | 0x1F));
}

// ---------------------------------------------------------- fused conv1+conv2
// Hadamard "conv" == 9-tap XOR-translate stencil:
//   out[i,j] = (1/n) * sum_{r,c<3} w[r,c] * S[i^r, j^c]
// (kern is rank<=9 sum of e_r e_c^T; Hu diag(Hu e_r) Hu = n * XOR-perm P_r.)
// No transforms, no transposes, no filter tables.
// Layout conv1: lane t = (row r=t>>1, half h=t&1), 16 contiguous cols.
//   j^1, j^2 intra-lane; i^1 = lane^2 (DPP), i^2 = lane^4 (ds_swizzle).
// Layout conv2: lane t = (slot f2s=t>>4, row rr=t&15), full 16-col row.
//   i^1 = lane^1 (DPP), i^2 = lane^2 (DPP).
__global__ __launch_bounds__(256) void k_conv(
    const float* __restrict__ x, const float* __restrict__ filt1,
    const float* __restrict__ bias1, const float* __restrict__ filt2,
    const float* __restrict__ bias2, unsigned short* __restrict__ Ah,
    unsigned short* __restrict__ Al) {
  __shared__ float sP[4 * 320];  // 4 waves x 16 rows x stride 20
  const int b = blockIdx.x;
  const int tid = threadIdx.x;
  const int wv = tid >> 6, t = tid & 63;

  // ---- S = sum_c x[b,c], own row per lane
  float s0[16];
  {
    const float* xb = x + (size_t)b * 3072 + (t >> 1) * 32 + (t & 1) * 16;
#pragma unroll
    for (int q = 0; q < 4; ++q) {
      float4 a0 = *(const float4*)(xb + 4 * q);
      float4 a1 = *(const float4*)(xb + 1024 + 4 * q);
      float4 a2 = *(const float4*)(xb + 2048 + 4 * q);
      s0[4 * q + 0] = a0.x + a1.x + a2.x;
      s0[4 * q + 1] = a0.y + a1.y + a2.y;
      s0[4 * q + 2] = a0.z + a1.z + a2.z;
      s0[4 * q + 3] = a0.w + a1.w + a2.w;
    }
  }
  // hoisted xor-row sets (shared across all 8 filters)
  float s1[16], s2[16];
#pragma unroll
  for (int k = 0; k < 16; ++k) s1[k] = lanex<2>(s0[k]);
#pragma unroll
  for (int k = 0; k < 16; ++k) s2[k] = lanex<4>(s0[k]);

  float acc[8];
#pragma unroll
  for (int j = 0; j < 8; ++j) acc[j] = 0.0f;

  // ---- conv1: 8 filters per wave, 9-tap stencil each
  for (int i = 0; i < 8; ++i) {
    const int f = __builtin_amdgcn_readfirstlane(wv * 8 + i);
    const float* fp = filt1 + f * 9;
    float w[9];
#pragma unroll
    for (int k = 0; k < 9; ++k) w[k] = fp[k] * (1.0f / 32.0f);
    const float bb = bias1[f];
    float u[16];
#pragma unroll
    for (int jj = 0; jj < 16; ++jj) {
      const int j1 = jj ^ 1, j2 = jj ^ 2;
      float v = fmaf(w[0], s0[jj], bb);
      v = fmaf(w[1], s0[j1], v);
      v = fmaf(w[2], s0[j2], v);
      v = fmaf(w[3], s1[jj], v);
      v = fmaf(w[4], s1[j1], v);
      v = fmaf(w[5], s1[j2], v);
      v = fmaf(w[6], s2[jj], v);
      v = fmaf(w[7], s2[j1], v);
      v = fmaf(w[8], s2[j2], v);
      u[jj] = fmaxf(v, 0.0f);
    }
    // pool rows (2i,2i+1): partner lane t^2
#pragma unroll
    for (int k = 0; k < 16; ++k) u[k] = fmaxf(u[k], lanex<2>(u[k]));
#pragma unroll
    for (int j = 0; j < 8; ++j) acc[j] += fmaxf(u[2 * j], u[2 * j + 1]);
  }

  // ---- per-wave partial S2 (16x16) -> LDS (stride 20)
  if (!(t & 2)) {
    const int pb = wv * 320 + (t >> 2) * 20 + (t & 1) * 8;
    *(float4*)&sP[pb] = make_float4(acc[0], acc[1], acc[2], acc[3]);
    *(float4*)&sP[pb + 4] = make_float4(acc[4], acc[5], acc[6], acc[7]);
  }
  __syncthreads();

  // ---- conv2: assemble S2 row rr, then 4 iterations of 4-filter slots
  const int f2s = t >> 4, rr = t & 15;
  float r0[16];
#pragma unroll
  for (int q = 0; q < 4; ++q) {
    float4 s = make_float4(0.f, 0.f, 0.f, 0.f);
#pragma unroll
    for (int w2 = 0; w2 < 4; ++w2) {
      const float4 v = *(const float4*)&sP[w2 * 320 + rr * 20 + 4 * q];
      s.x += v.x; s.y += v.y; s.z += v.z; s.w += v.w;
    }
    r0[4 * q + 0] = s.x;
    r0[4 * q + 1] = s.y;
    r0[4 * q + 2] = s.z;
    r0[4 * q + 3] = s.w;
  }
  float r1[16], r2[16];
#pragma unroll
  for (int k = 0; k < 16; ++k) r1[k] = lanex<1>(r0[k]);
#pragma unroll
  for (int k = 0; k < 16; ++k) r2[k] = lanex<2>(r0[k]);

#pragma unroll
  for (int it = 0; it < 4; ++it) {
    const int g = wv * 16 + it * 4 + f2s;
    const float* gp = filt2 + g * 9;
    float w[9];
#pragma unroll
    for (int k = 0; k < 9; ++k) w[k] = gp[k] * (1.0f / 16.0f);
    const float bb = bias2[g];
    float u[16];
#pragma unroll
    for (int jj = 0; jj < 16; ++jj) {
      const int j1 = jj ^ 1, j2 = jj ^ 2;
      float v = fmaf(w[0], r0[jj], bb);
      v = fmaf(w[1], r0[j1], v);
      v = fmaf(w[2], r0[j2], v);
      v = fmaf(w[3], r1[jj], v);
      v = fmaf(w[4], r1[j1], v);
      v = fmaf(w[5], r1[j2], v);
      v = fmaf(w[6], r2[jj], v);
      v = fmaf(w[7], r2[j1], v);
      v = fmaf(w[8], r2[j2], v);
      u[jj] = fmaxf(v, 0.0f);
    }
    // pool rows (rr, rr^1): partner lane t^1
#pragma unroll
    for (int k = 0; k < 16; ++k) u[k] = fmaxf(u[k], lanex<1>(u[k]));
    float p[8];
#pragma unroll
    for (int j = 0; j < 8; ++j) p[j] = fmaxf(u[2 * j], u[2 * j + 1]);
    if (!(t & 1)) {
      unsigned hh[4], ll[4];
#pragma unroll
      for (int j = 0; j < 4; ++j) split2(p[2 * j], p[2 * j + 1], hh[j], ll[j]);
      const size_t off = (size_t)b * 4096 + g * 64 + (rr >> 1) * 8;
      *(uint4*)(Ah + off) = make_uint4(hh[0], hh[1], hh[2], hh[3]);
      *(uint4*)(Al + off) = make_uint4(ll[0], ll[1], ll[2], ll[3]);
    }
  }
}

// ------------------------------------------------- W split fp32 -> bf16 hi/lo
__global__ __launch_bounds__(256) void k_wsplit(
    const float* __restrict__ W, unsigned short* __restrict__ Wh,
    unsigned short* __restrict__ Wl) {
  const int i = (blockIdx.x * 256 + threadIdx.x) * 4;
  float4 v = *(const float4*)(W + i);
  unsigned h0, l0, h1, l1;
  split2(v.x, v.y, h0, l0);
  split2(v.z, v.w, h1, l1);
  *(uint2*)(Wh + i) = make_uint2(h0, h1);
  *(uint2*)(Wl + i) = make_uint2(l0, l1);
}

// ------------------------------------------------------------------- FC1
// Split-bf16 MFMA GEMM, BM=128 BN=64 BK=64, split-K=4.
// Staging via global_load_lds (no VGPR round-trip, no spill):
//   LDS linear rows of 128B; per-lane GLOBAL source pre-swizzled by the
//   involution chunk^=(row&7); ds_read applies the same XOR -> conflict-free.
__global__ __launch_bounds__(256) void k_fc1(
    const unsigned short* __restrict__ Ah, const unsigned short* __restrict__ Al,
    const unsigned short* __restrict__ Wh, const unsigned short* __restrict__ Wl,
    float* __restrict__ P, int M) {
  // bytes: Ah [0,16384) Al [16384,32768) Wh [32768,40960) Wl [40960,49152)
  __shared__ __align__(16) unsigned char lds[49152];
  const int bid = blockIdx.x;
  const int low3 = bid & 7, rest = bid >> 3;
  const int nt = rest & 7;
  const int c = ((rest >> 3) << 3) | low3;  // (mt,kidx) chunk id
  const int mt = c >> 2, kidx = c & 3;
  const int m0 = mt * 128, n0 = nt * 64, k0 = kidx * 1024;

  const int tid = threadIdx.x;
  const int wv = tid >> 6, lane = tid & 63;
  const int wm = (wv >> 1) * 64, wn = (wv & 1) * 32;
  const int lm = lane & 15, lq = lane >> 4;
  const int lr = lane >> 3, lc = lane & 7;  // staging: row-in-issue, chunk

  float4x acc[4][2];
#pragma unroll
  for (int i = 0; i < 4; ++i)
#pragma unroll
    for (int j = 0; j < 2; ++j) acc[i][j] = (float4x){0.f, 0.f, 0.f, 0.f};

  for (int kk = 0; kk < 1024; kk += 64) {
    const int kcol = k0 + kk;
    // ---- stage A (hi/lo): wave wv rows wv*32..+31, 4 issues x 8 rows
#pragma unroll
    for (int it = 0; it < 4; ++it) {
      const int rbase = wv * 32 + it * 8;
      const int r = rbase + lr;
      const size_t go = (size_t)(m0 + r) * 4096 + kcol + (lc ^ (r & 7)) * 8;
      gload16(Ah + go, lds + rbase * 128);
      gload16(Al + go, lds + 16384 + rbase * 128);
    }
    // ---- stage W (hi/lo): wave wv rows wv*16..+15, 2 issues x 8 rows
#pragma unroll
    for (int it = 0; it < 2; ++it) {
      const int rbase = wv * 16 + it * 8;
      const int r = rbase + lr;
      const size_t go = (size_t)(n0 + r) * 4096 + kcol + (lc ^ (r & 7)) * 8;
      gload16(Wh + go, lds + 32768 + rbase * 128);
      gload16(Wl + go, lds + 40960 + rbase * 128);
    }
    __syncthreads();  // drains vmcnt(0): staging complete

    const uint4* l4 = (const uint4*)lds;
#pragma unroll
    for (int ks = 0; ks < 2; ++ks) {
      const int ch = ks * 4 + lq;
      short8x a_h[4], a_l[4], b_h[2], b_l[2];
#pragma unroll
      for (int fm = 0; fm < 4; ++fm) {
        const int r = wm + fm * 16 + lm;
        const int s = r * 8 + (ch ^ (r & 7));
        a_h[fm] = *(const short8x*)&l4[s];
        a_l[fm] = *(const short8x*)&l4[1024 + s];
      }
#pragma unroll
      for (int fn = 0; fn < 2; ++fn) {
        const int r = wn + fn * 16 + lm;
        const int s = r * 8 + (ch ^ (r & 7));
        b_h[fn] = *(const short8x*)&l4[2048 + s];
        b_l[fn] = *(const short8x*)&l4[2560 + s];
      }
#pragma unroll
      for (int fm = 0; fm < 4; ++fm)
#pragma unroll
        for (int fn = 0; fn < 2; ++fn) {
          acc[fm][fn] = __builtin_amdgcn_mfma_f32_16x16x32_bf16(
              a_h[fm], b_h[fn], acc[fm][fn], 0, 0, 0);
          acc[fm][fn] = __builtin_amdgcn_mfma_f32_16x16x32_bf16(
              a_h[fm], b_l[fn], acc[fm][fn], 0, 0, 0);
          acc[fm][fn] = __builtin_amdgcn_mfma_f32_16x16x32_bf16(
              a_l[fm], b_h[fn], acc[fm][fn], 0, 0, 0);
        }
    }
    __syncthreads();  // reads done before next stage overwrites
  }

  float* Pp = P + (size_t)kidx * ((size_t)M * 512);
#pragma unroll
  for (int fm = 0; fm < 4; ++fm)
#pragma unroll
    for (int fn = 0; fn < 2; ++fn)
#pragma unroll
      for (int i = 0; i < 4; ++i) {
        const int r = m0 + wm + fm * 16 + lq * 4 + i;
        const int cc = n0 + wn + fn * 16 + lm;
        Pp[(size_t)r * 512 + cc] = acc[fm][fn][i];
      }
}

__global__ __launch_bounds__(256) void k_fc1red4(
    const float* __restrict__ P, const float* __restrict__ bias,
    float* __restrict__ O, int total) {
  const int idx = (blockIdx.x * 256 + threadIdx.x) * 4;
  const float4 p0 = *(const float4*)(P + idx);
  const float4 p1 = *(const float4*)(P + (size_t)total + idx);
  const float4 p2 = *(const float4*)(P + (size_t)2 * total + idx);
  const float4 p3 = *(const float4*)(P + (size_t)3 * total + idx);
  const float4 bv = *(const float4*)(bias + (idx & 511));
  float4 o;
  o.x = fmaxf(p0.x + p1.x + p2.x + p3.x + bv.x, 0.0f);
  o.y = fmaxf(p0.y + p1.y + p2.y + p3.y + bv.y, 0.0f);
  o.z = fmaxf(p0.z + p1.z + p2.z + p3.z + bv.z, 0.0f);
  o.w = fmaxf(p0.w + p1.w + p2.w + p3.w + bv.w, 0.0f);
  *(float4*)(O + idx) = o;
}

// ------------------------------------------------------------- FC2+softmax
__global__ __launch_bounds__(256) void k_fc2(
    const float* __restrict__ X, const float* __restrict__ W,
    const float* __restrict__ bias, float* __restrict__ out) {
  const int wv = threadIdx.x >> 6, t = threadIdx.x & 63;
  const int b = blockIdx.x * 4 + wv;
  const float* xr = X + (size_t)b * 512 + t * 8;
  const float4 x0 = *(const float4*)xr;
  const float4 x1 = *(const float4*)(xr + 4);
  float z[10];
#pragma unroll
  for (int o = 0; o < 10; ++o) {
    const float* wr = W + o * 512 + t * 8;
    const float4 w0 = *(const float4*)wr;
    const float4 w1 = *(const float4*)(wr + 4);
    float s = x0.x * w0.x;
    s = fmaf(x0.y, w0.y, s);
    s = fmaf(x0.z, w0.z, s);
    s = fmaf(x0.w, w0.w, s);
    s = fmaf(x1.x, w1.x, s);
    s = fmaf(x1.y, w1.y, s);
    s = fmaf(x1.z, w1.z, s);
    s = fmaf(x1.w, w1.w, s);
    z[o] = s;
  }
#pragma unroll
  for (int m = 1; m < 64; m <<= 1) {
#pragma unroll
    for (int o = 0; o < 10; ++o) z[o] += shx(z[o], m);
  }
#pragma unroll
  for (int o = 0; o < 10; ++o) z[o] += bias[o];
  float mx = z[0];
#pragma unroll
  for (int o = 1; o < 10; ++o) mx = fmaxf(mx, z[o]);
  float e[10];
  float ssum = 0.0f;
#pragma unroll
  for (int o = 0; o < 10; ++o) {
    e[o] = expf(z[o] - mx);
    ssum += e[o];
  }
  const float inv = 1.0f / ssum;
  if (t == 0) {
    float* dst = out + (size_t)b * 10;
#pragma unroll
    for (int o = 0; o < 10; ++o) dst[o] = e[o] * inv;
  }
}

// ------------------------------------------------------------------ launch
extern "C" void kernel_launch(void* const* d_in, const int* in_sizes, int n_in,
                              void* d_out, int out_size, void* d_ws,
                              size_t ws_size, hipStream_t stream) {
  const float* x = (const float*)d_in[0];
  const float* f1 = (const float*)d_in[1];
  const float* b1 = (const float*)d_in[2];
  const float* f2 = (const float*)d_in[3];
  const float* b2 = (const float*)d_in[4];
  const float* fc1w = (const float*)d_in[5];
  const float* fc1b = (const float*)d_in[6];
  const float* fc2w = (const float*)d_in[7];
  const float* fc2b = (const float*)d_in[8];
  float* out = (float*)d_out;
  const int B = in_sizes[0] / 3072;  // 2048

  char* w = (char*)d_ws;
  unsigned short* Ah = (unsigned short*)w;  // B*4096 ushorts
  unsigned short* Al = (unsigned short*)(w + (size_t)B * 8192);
  unsigned short* Wh = (unsigned short*)(w + (size_t)2 * B * 8192);
  unsigned short* Wl = (unsigned short*)(w + (size_t)2 * B * 8192 + 4194304);
  float* P = (float*)(w + (size_t)2 * B * 8192 + 8388608);
  float* fc1o =
      (float*)(w + (size_t)2 * B * 8192 + 8388608 + (size_t)4 * B * 2048);

  hipLaunchKernelGGL(k_wsplit, dim3(2048), dim3(256), 0, stream, fc1w, Wh, Wl);
  hipLaunchKernelGGL(k_conv, dim3(B), dim3(256), 0, stream, x, f1, b1, f2, b2,
                     Ah, Al);
  hipLaunchKernelGGL(k_fc1, dim3((B / 128) * 32), dim3(256), 0, stream, Ah, Al,
                     Wh, Wl, P, B);
  hipLaunchKernelGGL(k_fc1red4, dim3((B * 512) / 1024), dim3(256), 0, stream,
                     P, fc1b, fc1o, B * 512);
  hipLaunchKernelGGL(k_fc2, dim3(B / 4), dim3(256), 0, stream, fc1o, fc2w,
                     fc2b, out);
}

// Round 7
// 154.829 us; speedup vs baseline: 1.7137x; 1.0030x over previous
//
#include <hip/hip_runtime.h>

#define DEVI __device__ __forceinline__

typedef __attribute__((ext_vector_type(8))) short short8x;
typedef __attribute__((ext_vector_type(4))) float float4x;

DEVI float shx(float v, int m) { return __shfl_xor(v, m, 64); }

DEVI unsigned bf16r(float v) {
  unsigned u = __float_as_uint(v);
  return (u + 0x7FFF + ((u >> 16) & 1)) >> 16;
}
// split two floats into packed bf16 hi-pair and lo-pair (RNE both levels)
DEVI void split2(float a, float b, unsigned& h, unsigned& l) {
  unsigned ra = bf16r(a), rb = bf16r(b);
  float fa = __uint_as_float(ra << 16), fb = __uint_as_float(rb << 16);
  unsigned la = bf16r(a - fa), lb = bf16r(b - fb);
  h = ra | (rb << 16);
  l = la | (lb << 16);
}

// async global->LDS, 16B per lane; LDS dest = wave-uniform base + lane*16
DEVI void gload16(const void* g, void* l) {
  __builtin_amdgcn_global_load_lds(
      (const __attribute__((address_space(1))) void*)g,
      (__attribute__((address_space(3))) void*)l, 16, 0, 0);
}

// Cross-lane xor-exchange. mask 1/2 -> DPP quad_perm; mask 4/8 -> ds_swizzle.
template <int MASK>
DEVI float lanex(float x) {
  if constexpr (MASK == 1)
    return __int_as_float(__builtin_amdgcn_update_dpp(
        0, __float_as_int(x), 0xB1, 0xF, 0xF, true));
  else if constexpr (MASK == 2)
    return __int_as_float(__builtin_amdgcn_update_dpp(
        0, __float_as_int(x), 0x4E, 0xF, 0xF, true));
  else
    return __int_as_float(__builtin_amdgcn_ds_swizzle(
        __float_as_int(x), (MASK << 10) | 0x1F));
}

// ---------------------------------------------------------- fused conv1+conv2
// Hadamard "conv" == 9-tap XOR-translate stencil:
//   out[i,j] = (1/n) * sum_{r,c<3} w[r,c] * S[i^r, j^c]
// 1/n folded into S once. relu folded into the column-pair max (max3).
// Column pool BEFORE cross-lane row pool (halves DPP traffic).
__global__ __launch_bounds__(256) void k_conv(
    const float* __restrict__ x, const float* __restrict__ filt1,
    const float* __restrict__ bias1, const float* __restrict__ filt2,
    const float* __restrict__ bias2, unsigned short* __restrict__ Ah,
    unsigned short* __restrict__ Al) {
  __shared__ float sP[4 * 320];  // 4 waves x 16 rows x stride 20
  const int b = blockIdx.x;
  const int tid = threadIdx.x;
  const int wv = tid >> 6, t = tid & 63;

  // ---- S = (1/32) * sum_c x[b,c], own row per lane
  float s0[16];
  {
    const float* xb = x + (size_t)b * 3072 + (t >> 1) * 32 + (t & 1) * 16;
#pragma unroll
    for (int q = 0; q < 4; ++q) {
      float4 a0 = *(const float4*)(xb + 4 * q);
      float4 a1 = *(const float4*)(xb + 1024 + 4 * q);
      float4 a2 = *(const float4*)(xb + 2048 + 4 * q);
      s0[4 * q + 0] = (a0.x + a1.x + a2.x) * (1.0f / 32.0f);
      s0[4 * q + 1] = (a0.y + a1.y + a2.y) * (1.0f / 32.0f);
      s0[4 * q + 2] = (a0.z + a1.z + a2.z) * (1.0f / 32.0f);
      s0[4 * q + 3] = (a0.w + a1.w + a2.w) * (1.0f / 32.0f);
    }
  }
  // hoisted xor-row sets (shared across all 8 filters)
  float s1[16], s2[16];
#pragma unroll
  for (int k = 0; k < 16; ++k) s1[k] = lanex<2>(s0[k]);
#pragma unroll
  for (int k = 0; k < 16; ++k) s2[k] = lanex<4>(s0[k]);

  float acc[8];
#pragma unroll
  for (int j = 0; j < 8; ++j) acc[j] = 0.0f;

  // ---- conv1: 8 filters per wave, 9-tap stencil each
  for (int i = 0; i < 8; ++i) {
    const int f = __builtin_amdgcn_readfirstlane(wv * 8 + i);
    const float* fp = filt1 + f * 9;
    float w[9];
#pragma unroll
    for (int k = 0; k < 9; ++k) w[k] = fp[k];
    const float bb = bias1[f];
    float c[8];
#pragma unroll
    for (int p = 0; p < 8; ++p) {
      const int ja = 2 * p, jb = ja ^ 1;
      const int ja2 = ja ^ 2, jb2 = jb ^ 2;
      float va = fmaf(w[0], s0[ja], bb);
      va = fmaf(w[1], s0[jb], va);
      va = fmaf(w[2], s0[ja2], va);
      va = fmaf(w[3], s1[ja], va);
      va = fmaf(w[4], s1[jb], va);
      va = fmaf(w[5], s1[ja2], va);
      va = fmaf(w[6], s2[ja], va);
      va = fmaf(w[7], s2[jb], va);
      va = fmaf(w[8], s2[ja2], va);
      float vb = fmaf(w[0], s0[jb], bb);
      vb = fmaf(w[1], s0[ja], vb);
      vb = fmaf(w[2], s0[jb2], vb);
      vb = fmaf(w[3], s1[jb], vb);
      vb = fmaf(w[4], s1[ja], vb);
      vb = fmaf(w[5], s1[jb2], vb);
      vb = fmaf(w[6], s2[jb], vb);
      vb = fmaf(w[7], s2[ja], vb);
      vb = fmaf(w[8], s2[jb2], vb);
      c[p] = fmaxf(fmaxf(va, vb), 0.0f);  // col-pair max + relu (v_max3)
    }
    // row pool: partner lane t^2; then accumulate channel-sum S2
#pragma unroll
    for (int p = 0; p < 8; ++p) acc[p] += fmaxf(c[p], lanex<2>(c[p]));
  }

  // ---- per-wave partial S2 (16x16) -> LDS (stride 20)
  if (!(t & 2)) {
    const int pb = wv * 320 + (t >> 2) * 20 + (t & 1) * 8;
    *(float4*)&sP[pb] = make_float4(acc[0], acc[1], acc[2], acc[3]);
    *(float4*)&sP[pb + 4] = make_float4(acc[4], acc[5], acc[6], acc[7]);
  }
  __syncthreads();

  // ---- conv2: assemble S2 row rr (scaled 1/16), 4 its of 4-filter slots
  const int f2s = t >> 4, rr = t & 15;
  float r0[16];
#pragma unroll
  for (int q = 0; q < 4; ++q) {
    float4 s = make_float4(0.f, 0.f, 0.f, 0.f);
#pragma unroll
    for (int w2 = 0; w2 < 4; ++w2) {
      const float4 v = *(const float4*)&sP[w2 * 320 + rr * 20 + 4 * q];
      s.x += v.x; s.y += v.y; s.z += v.z; s.w += v.w;
    }
    r0[4 * q + 0] = s.x * (1.0f / 16.0f);
    r0[4 * q + 1] = s.y * (1.0f / 16.0f);
    r0[4 * q + 2] = s.z * (1.0f / 16.0f);
    r0[4 * q + 3] = s.w * (1.0f / 16.0f);
  }
  float r1[16], r2[16];
#pragma unroll
  for (int k = 0; k < 16; ++k) r1[k] = lanex<1>(r0[k]);
#pragma unroll
  for (int k = 0; k < 16; ++k) r2[k] = lanex<2>(r0[k]);

#pragma unroll
  for (int it = 0; it < 4; ++it) {
    const int g = wv * 16 + it * 4 + f2s;
    const float* gp = filt2 + g * 9;
    float w[9];
#pragma unroll
    for (int k = 0; k < 9; ++k) w[k] = gp[k];
    const float bb = bias2[g];
    float c[8];
#pragma unroll
    for (int p = 0; p < 8; ++p) {
      const int ja = 2 * p, jb = ja ^ 1;
      const int ja2 = ja ^ 2, jb2 = jb ^ 2;
      float va = fmaf(w[0], r0[ja], bb);
      va = fmaf(w[1], r0[jb], va);
      va = fmaf(w[2], r0[ja2], va);
      va = fmaf(w[3], r1[ja], va);
      va = fmaf(w[4], r1[jb], va);
      va = fmaf(w[5], r1[ja2], va);
      va = fmaf(w[6], r2[ja], va);
      va = fmaf(w[7], r2[jb], va);
      va = fmaf(w[8], r2[ja2], va);
      float vb = fmaf(w[0], r0[jb], bb);
      vb = fmaf(w[1], r0[ja], vb);
      vb = fmaf(w[2], r0[jb2], vb);
      vb = fmaf(w[3], r1[jb], vb);
      vb = fmaf(w[4], r1[ja], vb);
      vb = fmaf(w[5], r1[jb2], vb);
      vb = fmaf(w[6], r2[jb], vb);
      vb = fmaf(w[7], r2[ja], vb);
      vb = fmaf(w[8], r2[jb2], vb);
      c[p] = fmaxf(fmaxf(va, vb), 0.0f);
    }
    // row pool: partner lane t^1 (rows rr, rr^1)
#pragma unroll
    for (int p = 0; p < 8; ++p) c[p] = fmaxf(c[p], lanex<1>(c[p]));
    if (!(t & 1)) {
      unsigned hh[4], ll[4];
#pragma unroll
      for (int j = 0; j < 4; ++j) split2(c[2 * j], c[2 * j + 1], hh[j], ll[j]);
      const size_t off = (size_t)b * 4096 + g * 64 + (rr >> 1) * 8;
      *(uint4*)(Ah + off) = make_uint4(hh[0], hh[1], hh[2], hh[3]);
      *(uint4*)(Al + off) = make_uint4(ll[0], ll[1], ll[2], ll[3]);
    }
  }
}

// ------------------------------------------------- W split fp32 -> bf16 hi/lo
__global__ __launch_bounds__(256) void k_wsplit(
    const float* __restrict__ W, unsigned short* __restrict__ Wh,
    unsigned short* __restrict__ Wl) {
  const int i = (blockIdx.x * 256 + threadIdx.x) * 4;
  float4 v = *(const float4*)(W + i);
  unsigned h0, l0, h1, l1;
  split2(v.x, v.y, h0, l0);
  split2(v.z, v.w, h1, l1);
  *(uint2*)(Wh + i) = make_uint2(h0, h1);
  *(uint2*)(Wl + i) = make_uint2(l0, l1);
}

// ------------------------------------------------------------------- FC1
// Split-bf16 MFMA GEMM, BM=128 BN=64 BK=32, split-K=4, double-buffered LDS
// 2x24KB with 2-phase pipeline: STAGE(t+1) issued BEFORE compute(t), one
// barrier per iter (compiler emits vmcnt(0) drain at the barrier).
// LDS row = 128B = 8 chunks {hi k0..k3, lo k0..k3}; involution p <-> p^(r&7)
// applied on the GLOBAL source (per-lane addr) and the ds_read, LDS linear.
__global__ __launch_bounds__(256) void k_fc1(
    const unsigned short* __restrict__ Ah, const unsigned short* __restrict__ Al,
    const unsigned short* __restrict__ Wh, const unsigned short* __restrict__ Wl,
    float* __restrict__ P, int M) {
  // per buffer: A 128 rows x 128B = 16KB at +0, W 64 rows x 128B = 8KB at +16K
  __shared__ __align__(16) unsigned char lds[49152];
  const int bid = blockIdx.x;
  const int low3 = bid & 7, rest = bid >> 3;
  const int nt = rest & 7;
  const int c = ((rest >> 3) << 3) | low3;  // (mt,kidx) chunk id
  const int mt = c >> 2, kidx = c & 3;
  const int m0 = mt * 128, n0 = nt * 64, k0 = kidx * 1024;

  const int tid = threadIdx.x;
  const int wv = tid >> 6, lane = tid & 63;
  const int wm = (wv >> 1) * 64, wn = (wv & 1) * 32;
  const int lm = lane & 15, lq = lane >> 4;

  float4x acc[4][2];
#pragma unroll
  for (int i = 0; i < 4; ++i)
#pragma unroll
    for (int j = 0; j < 2; ++j) acc[i][j] = (float4x){0.f, 0.f, 0.f, 0.f};

  // stage K-step st into buffer at byte base bb
  auto stage = [&](int st, int bb) {
    const int kcol = k0 + st * 32;
    const int rj = lane >> 3;       // row within 8-row issue
    const int pj = lane & 7;        // physical chunk
#pragma unroll
    for (int it = 0; it < 4; ++it) {  // A: 32 rows per wave
      const int rb = wv * 32 + it * 8;
      const int r = rb + rj;
      const int l = pj ^ (r & 7);
      const unsigned short* src = (l < 4) ? Ah : Al;
      const size_t go = (size_t)(m0 + r) * 4096 + kcol + (l & 3) * 8;
      gload16(src + go, lds + bb + rb * 128);
    }
#pragma unroll
    for (int it = 0; it < 2; ++it) {  // W: 16 rows per wave
      const int rb = wv * 16 + it * 8;
      const int r = rb + rj;
      const int l = pj ^ (r & 7);
      const unsigned short* src = (l < 4) ? Wh : Wl;
      const size_t go = (size_t)(n0 + r) * 4096 + kcol + (l & 3) * 8;
      gload16(src + go, lds + bb + 16384 + rb * 128);
    }
  };

  stage(0, 0);
  __syncthreads();

  for (int st = 0; st < 32; ++st) {
    const int bb = (st & 1) * 24576;
    if (st < 31) stage(st + 1, bb ^ 24576);  // overlap with compute below

    short8x a_h[4], a_l[4], b_h[2], b_l[2];
#pragma unroll
    for (int fm = 0; fm < 4; ++fm) {
      const int r = wm + fm * 16 + lm;
      const unsigned char* base = lds + bb + r * 128;
      a_h[fm] = *(const short8x*)(base + (lq ^ (r & 7)) * 16);
      a_l[fm] = *(const short8x*)(base + ((lq ^ 4) ^ (r & 7)) * 16);
    }
#pragma unroll
    for (int fn = 0; fn < 2; ++fn) {
      const int r = wn + fn * 16 + lm;
      const unsigned char* base = lds + bb + 16384 + r * 128;
      b_h[fn] = *(const short8x*)(base + (lq ^ (r & 7)) * 16);
      b_l[fn] = *(const short8x*)(base + ((lq ^ 4) ^ (r & 7)) * 16);
    }
#pragma unroll
    for (int fm = 0; fm < 4; ++fm)
#pragma unroll
      for (int fn = 0; fn < 2; ++fn) {
        acc[fm][fn] = __builtin_amdgcn_mfma_f32_16x16x32_bf16(
            a_h[fm], b_h[fn], acc[fm][fn], 0, 0, 0);
        acc[fm][fn] = __builtin_amdgcn_mfma_f32_16x16x32_bf16(
            a_h[fm], b_l[fn], acc[fm][fn], 0, 0, 0);
        acc[fm][fn] = __builtin_amdgcn_mfma_f32_16x16x32_bf16(
            a_l[fm], b_h[fn], acc[fm][fn], 0, 0, 0);
      }
    __syncthreads();  // reads done + next stage landed
  }

  float* Pp = P + (size_t)kidx * ((size_t)M * 512);
#pragma unroll
  for (int fm = 0; fm < 4; ++fm)
#pragma unroll
    for (int fn = 0; fn < 2; ++fn)
#pragma unroll
      for (int i = 0; i < 4; ++i) {
        const int r = m0 + wm + fm * 16 + lq * 4 + i;
        const int cc = n0 + wn + fn * 16 + lm;
        Pp[(size_t)r * 512 + cc] = acc[fm][fn][i];
      }
}

// --------------------------------------- FC2 (+ fused split-K red + softmax)
__global__ __launch_bounds__(256) void k_fc2(
    const float* __restrict__ P, const float* __restrict__ bias1,
    const float* __restrict__ W, const float* __restrict__ bias2,
    float* __restrict__ out, int M) {
  const int wv = threadIdx.x >> 6, t = threadIdx.x & 63;
  const int b = blockIdx.x * 4 + wv;
  const size_t ks = (size_t)M * 512;
  const float* pr = P + (size_t)b * 512 + t * 8;
  float4 u0 = *(const float4*)pr;
  float4 u1 = *(const float4*)(pr + 4);
#pragma unroll
  for (int k = 1; k < 4; ++k) {
    const float4 v0 = *(const float4*)(pr + k * ks);
    const float4 v1 = *(const float4*)(pr + k * ks + 4);
    u0.x += v0.x; u0.y += v0.y; u0.z += v0.z; u0.w += v0.w;
    u1.x += v1.x; u1.y += v1.y; u1.z += v1.z; u1.w += v1.w;
  }
  const float4 bb0 = *(const float4*)(bias1 + t * 8);
  const float4 bb1 = *(const float4*)(bias1 + t * 8 + 4);
  float a[8];
  a[0] = fmaxf(u0.x + bb0.x, 0.0f);
  a[1] = fmaxf(u0.y + bb0.y, 0.0f);
  a[2] = fmaxf(u0.z + bb0.z, 0.0f);
  a[3] = fmaxf(u0.w + bb0.w, 0.0f);
  a[4] = fmaxf(u1.x + bb1.x, 0.0f);
  a[5] = fmaxf(u1.y + bb1.y, 0.0f);
  a[6] = fmaxf(u1.z + bb1.z, 0.0f);
  a[7] = fmaxf(u1.w + bb1.w, 0.0f);
  float z[10];
#pragma unroll
  for (int o = 0; o < 10; ++o) {
    const float* wr = W + o * 512 + t * 8;
    const float4 w0 = *(const float4*)wr;
    const float4 w1 = *(const float4*)(wr + 4);
    float s = a[0] * w0.x;
    s = fmaf(a[1], w0.y, s);
    s = fmaf(a[2], w0.z, s);
    s = fmaf(a[3], w0.w, s);
    s = fmaf(a[4], w1.x, s);
    s = fmaf(a[5], w1.y, s);
    s = fmaf(a[6], w1.z, s);
    s = fmaf(a[7], w1.w, s);
    z[o] = s;
  }
#pragma unroll
  for (int m = 1; m < 64; m <<= 1) {
#pragma unroll
    for (int o = 0; o < 10; ++o) z[o] += shx(z[o], m);
  }
#pragma unroll
  for (int o = 0; o < 10; ++o) z[o] += bias2[o];
  float mx = z[0];
#pragma unroll
  for (int o = 1; o < 10; ++o) mx = fmaxf(mx, z[o]);
  float e[10];
  float ssum = 0.0f;
#pragma unroll
  for (int o = 0; o < 10; ++o) {
    e[o] = expf(z[o] - mx);
    ssum += e[o];
  }
  const float inv = 1.0f / ssum;
  if (t == 0) {
    float* dst = out + (size_t)b * 10;
#pragma unroll
    for (int o = 0; o < 10; ++o) dst[o] = e[o] * inv;
  }
}

// ------------------------------------------------------------------ launch
extern "C" void kernel_launch(void* const* d_in, const int* in_sizes, int n_in,
                              void* d_out, int out_size, void* d_ws,
                              size_t ws_size, hipStream_t stream) {
  const float* x = (const float*)d_in[0];
  const float* f1 = (const float*)d_in[1];
  const float* b1 = (const float*)d_in[2];
  const float* f2 = (const float*)d_in[3];
  const float* b2 = (const float*)d_in[4];
  const float* fc1w = (const float*)d_in[5];
  const float* fc1b = (const float*)d_in[6];
  const float* fc2w = (const float*)d_in[7];
  const float* fc2b = (const float*)d_in[8];
  float* out = (float*)d_out;
  const int B = in_sizes[0] / 3072;  // 2048

  char* w = (char*)d_ws;
  unsigned short* Ah = (unsigned short*)w;  // B*4096 ushorts
  unsigned short* Al = (unsigned short*)(w + (size_t)B * 8192);
  unsigned short* Wh = (unsigned short*)(w + (size_t)2 * B * 8192);
  unsigned short* Wl = (unsigned short*)(w + (size_t)2 * B * 8192 + 4194304);
  float* P = (float*)(w + (size_t)2 * B * 8192 + 8388608);

  hipLaunchKernelGGL(k_wsplit, dim3(2048), dim3(256), 0, stream, fc1w, Wh, Wl);
  hipLaunchKernelGGL(k_conv, dim3(B), dim3(256), 0, stream, x, f1, b1, f2, b2,
                     Ah, Al);
  hipLaunchKernelGGL(k_fc1, dim3((B / 128) * 32), dim3(256), 0, stream, Ah, Al,
                     Wh, Wl, P, B);
  hipLaunchKernelGGL(k_fc2, dim3(B / 4), dim3(256), 0, stream, P, fc1b, fc2w,
                     fc2b, out, B);
}